// Round 4
// baseline (53.333 us; speedup 1.0000x reference)
//
#include <hip/hip_runtime.h>
#include <math.h>

#define D 128
#define N 256
#define B 4

#define LOG2E 1.44269504f
#define LN2   0.69314718f
#define PROJ_R 0.996f

__device__ __forceinline__ float frcp(float x)  { return __builtin_amdgcn_rcpf(x); }
__device__ __forceinline__ float fexp(float x)  { return __builtin_amdgcn_exp2f(x * LOG2E); }
__device__ __forceinline__ float fsilu(float v) { return v * frcp(1.f + fexp(-v)); }
__device__ __forceinline__ float fsigm(float v) { return frcp(1.f + fexp(-v)); }

__device__ __forceinline__ float fartanh(float z) {
  z = fminf(fmaxf(z, -1.f + 1e-7f), 1.f - 1e-7f);
  return 0.5f * LN2 * __builtin_amdgcn_logf((1.f + z) * frcp(1.f - z));
}
// tanh for x >= 0 (all our args are norms)
__device__ __forceinline__ float ftanh(float x) {
  float t = __builtin_amdgcn_exp2f(2.f * LOG2E * x);
  return (t - 1.f) * frcp(t + 1.f);
}

__device__ __forceinline__ float wave_sum(float v) {
  #pragma unroll
  for (int off = 32; off; off >>= 1) v += __shfl_xor(v, off, 64);
  return v;
}

// ---- per-128-thread-group reductions in a 512-thread block (4 groups x 2 waves) ----
// red must be float[16]; all 512 threads must call (uniform control flow).
__device__ __forceinline__ float group_sum(float v, float* red) {
  v = wave_sum(v);
  const int grp = threadIdx.x >> 7;
  const int wid = (threadIdx.x >> 6) & 1;
  __syncthreads();
  if ((threadIdx.x & 63) == 0) red[grp * 2 + wid] = v;
  __syncthreads();
  return red[grp * 2] + red[grp * 2 + 1];
}

__device__ __forceinline__ float2 group_sum2(float a, float b, float* red) {
  a = wave_sum(a);
  b = wave_sum(b);
  const int grp = threadIdx.x >> 7;
  const int wid = (threadIdx.x >> 6) & 1;
  __syncthreads();
  if ((threadIdx.x & 63) == 0) { red[grp * 4 + wid * 2] = a; red[grp * 4 + wid * 2 + 1] = b; }
  __syncthreads();
  return make_float2(red[grp * 4] + red[grp * 4 + 2], red[grp * 4 + 1] + red[grp * 4 + 3]);
}

// ---------- kernel 1: per-node HypLinear (h, nh2) + u ----------
// 512 threads = 4 nodes x 128 dims. Weights consumed row-major (L2/L1-hot).
__global__ __launch_bounds__(512) void k_node(
    const float* __restrict__ x, const float* __restrict__ W,
    const float* __restrict__ aw1, const float* __restrict__ b_lin,
    float* __restrict__ h, float* __restrict__ u, float* __restrict__ nh2) {
  const int grp = threadIdx.x >> 7;
  const int k   = threadIdx.x & 127;
  const int node = blockIdx.x * 4 + grp;
  __shared__ __align__(16) float vl[4][D];
  __shared__ float red[16];

  // hyp_bias = proj(expmap0(b_lin)) — redundant per block, cheap. ||e|| = tanh(||b||).
  float bv = b_lin[k];
  float bn2 = group_sum(bv * bv, red);
  float bn = fmaxf(sqrtf(bn2), 1e-15f);
  float tb = tanhf(bn);
  float hbk = tb * bv * frcp(bn);
  float hb2 = tb * tb;
  if (tb > PROJ_R) { hbk *= PROJ_R * frcp(tb); hb2 = PROJ_R * PROJ_R; }

  float xv = x[node * D + k];
  vl[grp][k] = xv;
  float xn2 = group_sum(xv * xv, red);   // syncs publish vl

  // mx = W @ x : thread k streams row k of W
  const float4* Wr = (const float4*)(W + k * D);
  float mxa = 0.f, mxb = 0.f;
  #pragma unroll 8
  for (int m4 = 0; m4 < D / 4; ++m4) {
    float4 w4 = Wr[m4];
    const float4 vm = *(const float4*)&vl[grp][m4 * 4];
    mxa = fmaf(w4.x, vm.x, mxa); mxb = fmaf(w4.y, vm.y, mxb);
    mxa = fmaf(w4.z, vm.z, mxa); mxb = fmaf(w4.w, vm.w, mxb);
  }
  float mx = mxa + mxb;
  float mxn2 = group_sum(mx * mx, red);

  float xn  = fmaxf(sqrtf(xn2), 1e-15f);
  float mxn = fmaxf(sqrtf(mxn2), 1e-15f);
  float r = ftanh(mxn * frcp(xn) * fartanh(xn));
  float res = r * mx * frcp(mxn);

  // proj + (res . hyp_bias) fused
  float2 rp = group_sum2(res * res, res * hbk, red);
  float rn2 = rp.x, xy = rp.y;
  float rn = fmaxf(sqrtf(rn2), 1e-15f);
  float x2 = rn2;
  if (rn > PROJ_R) { float sc = PROJ_R * frcp(rn); res *= sc; xy *= sc; x2 = PROJ_R * PROJ_R; }

  // mobius_add(res, hyp_bias), then proj
  float num = (1.f + 2.f * xy + hb2) * res + (1.f - x2) * hbk;
  float den = fmaxf(1.f + 2.f * xy + x2 * hb2, 1e-15f);
  float hv = num * frcp(den);
  float hn2 = group_sum(hv * hv, red);
  float hn = fmaxf(sqrtf(hn2), 1e-15f);
  float h2 = hn2;
  if (hn > PROJ_R) { hv = hv * frcp(hn) * PROJ_R; h2 = PROJ_R * PROJ_R; }

  h[node * D + k] = hv;
  if (k == 0) nh2[node] = h2;

  // u = att_w1[:, D:2D] @ h : thread k streams row k (cols D..2D) of att_w1
  __syncthreads();
  vl[grp][k] = hv;
  __syncthreads();
  const float4* Ar = (const float4*)(aw1 + k * (2 * D) + D);
  float ua = 0.f, ub = 0.f;
  #pragma unroll 8
  for (int m4 = 0; m4 < D / 4; ++m4) {
    float4 w4 = Ar[m4];
    const float4 vm = *(const float4*)&vl[grp][m4 * 4];
    ua = fmaf(w4.x, vm.x, ua); ub = fmaf(w4.y, vm.y, ub);
    ua = fmaf(w4.z, vm.z, ua); ub = fmaf(w4.w, vm.w, ub);
  }
  u[node * D + k] = ua + ub;
}

// ---------- kernel 2: fused attention (active pairs only) + support + MLP + maps ----------
// 512 threads = 4 nodes; mask compacted per node (deterministic wave-order prefix).
__global__ __launch_bounds__(512) void k_fused(
    const float* __restrict__ h, const float* __restrict__ u,
    const float* __restrict__ nh2, const float* __restrict__ mask,
    const float* __restrict__ ab1, const float* __restrict__ aw2,
    const float* __restrict__ ab2,
    const float* __restrict__ mw1, const float* __restrict__ mb1,
    const float* __restrict__ mw2, const float* __restrict__ mb2,
    float* __restrict__ out) {
  const int t = threadIdx.x;
  const int grp = t >> 7;
  const int k = t & 127;
  const int node = blockIdx.x * 4 + grp;
  const int bb = node >> 8;
  __shared__ __align__(16) float hi[4][D], ui[4][D], b1l[D], w2l[D];
  __shared__ __align__(16) float sl[4][D], gl[4][D];
  __shared__ float wBs[4][N];
  __shared__ int actJ[4][N];
  __shared__ int wcnt[4][4];
  __shared__ int nacts[4];
  __shared__ float red[16];

  // ---- stage per-node vectors ----
  hi[grp][k] = h[node * D + k];
  ui[grp][k] = u[node * D + k];
  if (t < D) { b1l[t] = ab1[t]; w2l[t] = aw2[t]; }

  // ---- deterministic mask compaction: 2 passes x (2 rows x 4 waves) ----
  const int lane = t & 63;
  const int wrow = (t >> 6) & 3;     // wave index within its 256-thread row
  bool actv[2]; int prev[2];
  #pragma unroll
  for (int r = 0; r < 2; ++r) {
    const int ii = r * 2 + (t >> 8);
    const int j = t & 255;
    float mk = mask[(blockIdx.x * 4 + ii) * N + j];
    bool a = (mk != 0.f);
    unsigned long long bal = __ballot(a);
    actv[r] = a;
    prev[r] = __popcll(bal & ((1ull << lane) - 1ull));
    if (lane == 0) wcnt[ii][wrow] = __popcll(bal);
  }
  __syncthreads();
  #pragma unroll
  for (int r = 0; r < 2; ++r) {
    const int ii = r * 2 + (t >> 8);
    int base = 0;
    for (int w = 0; w < wrow; ++w) base += wcnt[ii][w];
    if (actv[r]) actJ[ii][base + prev[r]] = t & 255;
  }
  if (t < 4) nacts[t] = wcnt[t][0] + wcnt[t][1] + wcnt[t][2] + wcnt[t][3];
  __syncthreads();

  // ---- phase B: per-active-pair logmap scalars + DenseAtt MLP ----
  const float bias2 = ab2[0];
  float wA_v = 0.f;
  {
    const int nact = nacts[grp];
    const float n2i = nh2[node];
    const float beta = 1.f - n2i;
    const float coefb = fmaxf(beta, 1e-15f);
    for (int idx = k; idx < nact; idx += 128) {
      const int j = actJ[grp][idx];
      const int jrow = bb * N + j;
      const float n2j = nh2[jrow];
      const float4* hj = (const float4*)(h + jrow * D);
      const float4* hi4 = (const float4*)hi[grp];
      float g0 = 0.f, g1 = 0.f;
      #pragma unroll 8
      for (int m4 = 0; m4 < D / 4; ++m4) {
        float4 a4 = hi4[m4], v4 = hj[m4];
        g0 = fmaf(a4.x, v4.x, g0); g1 = fmaf(a4.y, v4.y, g1);
        g0 = fmaf(a4.z, v4.z, g0); g1 = fmaf(a4.w, v4.w, g1);
      }
      float g = g0 + g1;
      float alpha = 1.f - 2.f * g + n2j;
      float den = fmaxf(1.f - 2.f * g + n2i * n2j, 1e-15f);
      float rden = frcp(den);
      float A0 = -alpha * rden, B0 = beta * rden;
      float sn2 = fmaxf(A0 * A0 * n2i + 2.f * A0 * B0 * g + B0 * B0 * n2j, 0.f);
      float sn = fmaxf(sqrtf(sn2), 1e-15f);
      float coef = coefb * fartanh(sn) * frcp(sn);
      float A = coef * A0, Bc = coef * B0;

      const float4* uj = (const float4*)(u + jrow * D);
      const float4* ui4 = (const float4*)ui[grp];
      const float4* b14 = (const float4*)b1l;
      const float4* w24 = (const float4*)w2l;
      float acc0 = 0.f, acc1 = 0.f;
      #pragma unroll 4
      for (int m4 = 0; m4 < D / 4; ++m4) {
        float4 uu = uj[m4], vv = ui4[m4], bb4 = b14[m4], ww = w24[m4];
        acc0 = fmaf(fsilu(fmaf(A, vv.x, fmaf(Bc, uu.x, bb4.x))), ww.x, acc0);
        acc1 = fmaf(fsilu(fmaf(A, vv.y, fmaf(Bc, uu.y, bb4.y))), ww.y, acc1);
        acc0 = fmaf(fsilu(fmaf(A, vv.z, fmaf(Bc, uu.z, bb4.z))), ww.z, acc0);
        acc1 = fmaf(fsilu(fmaf(A, vv.w, fmaf(Bc, uu.w, bb4.w))), ww.w, acc1);
      }
      float w = fsigm(acc0 + acc1 + bias2);   // mask == 1 for active pairs
      wBs[grp][idx] = w * Bc;
      wA_v += w * A;
    }
  }
  float accA = group_sum(wA_v, red);   // syncs also publish wBs/actJ reuse

  // ---- phase C: support_t[k] = accA*h_i[k] + sum_p wB[p]*h_j[p][k] ----
  const int nact_g = nacts[grp];
  float s0 = accA * hi[grp][k], s1 = 0.f;
  int p = 0;
  for (; p + 2 <= nact_g; p += 2) {
    s0 = fmaf(wBs[grp][p],     h[(bb * N + actJ[grp][p]) * D + k],     s0);
    s1 = fmaf(wBs[grp][p + 1], h[(bb * N + actJ[grp][p + 1]) * D + k], s1);
  }
  if (p < nact_g) s0 = fmaf(wBs[grp][p], h[(bb * N + actJ[grp][p]) * D + k], s0);
  sl[grp][k] = s0 + s1;
  __syncthreads();

  // ---- phase D: node MLP (x_self half ~ 0): row-streamed weights ----
  const float4* w1r = (const float4*)(mw1 + k * (2 * D) + D);
  float a0 = mb1[k], a1 = 0.f;
  #pragma unroll 8
  for (int m4 = 0; m4 < D / 4; ++m4) {
    float4 w4 = w1r[m4];
    const float4 sv = *(const float4*)&sl[grp][m4 * 4];
    a0 = fmaf(w4.x, sv.x, a0); a1 = fmaf(w4.y, sv.y, a1);
    a0 = fmaf(w4.z, sv.z, a0); a1 = fmaf(w4.w, sv.w, a1);
  }
  gl[grp][k] = fsilu(a0 + a1);
  __syncthreads();
  const float4* w2r = (const float4*)(mw2 + k * D);
  float c0 = mb2[k], c1 = 0.f;
  #pragma unroll 8
  for (int m4 = 0; m4 < D / 4; ++m4) {
    float4 w4 = w2r[m4];
    const float4 gv = *(const float4*)&gl[grp][m4 * 4];
    c0 = fmaf(w4.x, gv.x, c0); c1 = fmaf(w4.y, gv.y, c1);
    c0 = fmaf(w4.z, gv.z, c0); c1 = fmaf(w4.w, gv.w, c1);
  }
  float s2 = c0 + c1;

  // ---- phase E: expmap(s2, h) -> proj -> HypAct (analytic norms) ----
  const float hk = hi[grp][k];
  const float n2p = nh2[node];
  float2 us = group_sum2(s2 * s2, hk * s2, red);
  float un = fmaxf(sqrtf(us.x), 1e-15f);
  float lam = 2.f * frcp(fmaxf(1.f - n2p, 1e-15f));
  float th = ftanh(0.5f * lam * un);
  float ssc = th * frcp(un);
  float second = ssc * s2;
  float y2 = th * th;            // ||second||^2
  float xy = ssc * us.y;         // h . second

  float num = (1.f + 2.f * xy + y2) * hk + (1.f - n2p) * second;
  float den = fmaxf(1.f + 2.f * xy + n2p * y2, 1e-15f);
  float o = num * frcp(den);

  float on2 = group_sum(o * o, red);
  float on = fmaxf(sqrtf(on2), 1e-15f);
  float pn = on;
  if (on > PROJ_R) { o *= PROJ_R * frcp(on); pn = PROJ_R; }

  float xt = fartanh(pn) * frcp(pn) * o;
  xt = fsilu(xt);
  float xn2 = group_sum(xt * xt, red);
  float xn = fmaxf(sqrtf(xn2), 1e-15f);
  float tx = ftanh(xn);
  float o2 = tx * frcp(xn) * xt;
  if (tx > PROJ_R) o2 *= PROJ_R * frcp(tx);   // ||o2|| == tx analytically

  out[node * D + k] = o2;
}

// ---------- launch ----------
extern "C" void kernel_launch(void* const* d_in, const int* in_sizes, int n_in,
                              void* d_out, int out_size, void* d_ws, size_t ws_size,
                              hipStream_t stream) {
  const float* x     = (const float*)d_in[0];
  const float* mask  = (const float*)d_in[1];
  const float* W     = (const float*)d_in[2];
  const float* b_lin = (const float*)d_in[3];
  const float* aw1   = (const float*)d_in[4];
  const float* ab1   = (const float*)d_in[5];
  const float* aw2   = (const float*)d_in[6];
  const float* ab2   = (const float*)d_in[7];
  const float* mw1   = (const float*)d_in[8];
  const float* mb1   = (const float*)d_in[9];
  const float* mw2   = (const float*)d_in[10];
  const float* mb2   = (const float*)d_in[11];
  float* out = (float*)d_out;

  float* ws  = (float*)d_ws;
  float* h   = ws;               // B*N*D = 131072
  float* u   = h + B * N * D;    // B*N*D = 131072
  float* nh2 = u + B * N * D;    // B*N   = 1024

  hipLaunchKernelGGL(k_node, dim3(B * N / 4), dim3(512), 0, stream,
                     x, W, aw1, b_lin, h, u, nh2);
  hipLaunchKernelGGL(k_fused, dim3(B * N / 4), dim3(512), 0, stream,
                     h, u, nh2, mask, ab1, aw2, ab2, mw1, mb1, mw2, mb2, out);
}

// Round 5
// 40.423 us; speedup vs baseline: 1.3194x; 1.3194x over previous
//
#include <hip/hip_runtime.h>
#include <math.h>

#define D 128
#define N 256
#define B 4

#define LOG2E 1.44269504f
#define LN2   0.69314718f
#define PROJ_R 0.996f

__device__ __forceinline__ float frcp(float x)  { return __builtin_amdgcn_rcpf(x); }
__device__ __forceinline__ float fexp(float x)  { return __builtin_amdgcn_exp2f(x * LOG2E); }
__device__ __forceinline__ float fsilu(float v) { return v * frcp(1.f + fexp(-v)); }
__device__ __forceinline__ float fsigm(float v) { return frcp(1.f + fexp(-v)); }

__device__ __forceinline__ float fartanh(float z) {
  z = fminf(fmaxf(z, -1.f + 1e-7f), 1.f - 1e-7f);
  return 0.5f * LN2 * __builtin_amdgcn_logf((1.f + z) * frcp(1.f - z));
}
// tanh for x >= 0 (all our args are norms)
__device__ __forceinline__ float ftanh(float x) {
  float t = __builtin_amdgcn_exp2f(2.f * LOG2E * x);
  return (t - 1.f) * frcp(t + 1.f);
}

__device__ __forceinline__ float wave_sum(float v) {
  #pragma unroll
  for (int off = 32; off; off >>= 1) v += __shfl_xor(v, off, 64);
  return v;
}

// ---- per-128-thread-group reductions in a 512-thread block ----
__device__ __forceinline__ float group_sum(float v, float* red) {
  v = wave_sum(v);
  const int grp = threadIdx.x >> 7;
  const int wid = (threadIdx.x >> 6) & 1;
  __syncthreads();
  if ((threadIdx.x & 63) == 0) red[grp * 2 + wid] = v;
  __syncthreads();
  return red[grp * 2] + red[grp * 2 + 1];
}

__device__ __forceinline__ float2 group_sum2(float a, float b, float* red) {
  a = wave_sum(a);
  b = wave_sum(b);
  const int grp = threadIdx.x >> 7;
  const int wid = (threadIdx.x >> 6) & 1;
  __syncthreads();
  if ((threadIdx.x & 63) == 0) { red[grp * 4 + wid * 2] = a; red[grp * 4 + wid * 2 + 1] = b; }
  __syncthreads();
  return make_float2(red[grp * 4] + red[grp * 4 + 2], red[grp * 4 + 1] + red[grp * 4 + 3]);
}

// ---------- kernel 1: per-node HypLinear (h, nh2) + u ----------
// 512 threads = 4 nodes x 128 dims. Matvecs are chunk-split: thread (k, c=grp)
// covers m in [32c,32c+32) of weight-row k for ALL 4 nodes -> weights read once
// per block (L2 traffic /4), partials combined via LDS.
__global__ __launch_bounds__(512) void k_node(
    const float* __restrict__ x, const float* __restrict__ W,
    const float* __restrict__ aw1, const float* __restrict__ b_lin,
    float* __restrict__ h, float* __restrict__ u, float* __restrict__ nh2) {
  const int t = threadIdx.x;
  const int grp = t >> 7;       // node-in-block (and chunk id inside matvecs)
  const int k   = t & 127;
  const int node = blockIdx.x * 4 + grp;
  __shared__ __align__(16) float vl[4][D];
  __shared__ __align__(16) float pacc[4][4][D];   // [chunk][node][k]
  __shared__ float red[16];

  float bv = b_lin[k];
  float xv = x[node * D + k];
  vl[grp][k] = xv;
  float2 bx = group_sum2(bv * bv, xv * xv, red);  // bn2, xn2; syncs publish vl

  // hyp_bias = proj(expmap0(b_lin)): ||e|| = tanh(||b||)
  float bn = fmaxf(sqrtf(bx.x), 1e-15f);
  float tb = ftanh(bn);
  float hbk = tb * bv * frcp(bn);
  float hb2 = tb * tb;
  if (tb > PROJ_R) { hbk *= PROJ_R * frcp(tb); hb2 = PROJ_R * PROJ_R; }
  const float xn2 = bx.y;

  // ---- mx = W @ x, chunk-split ----
  {
    const float4* Wr = (const float4*)(W + k * D + grp * 32);
    float a0 = 0.f, a1 = 0.f, a2 = 0.f, a3 = 0.f;
    #pragma unroll
    for (int m4 = 0; m4 < 8; ++m4) {
      float4 w4 = Wr[m4];
      const int mb = grp * 32 + m4 * 4;
      float4 v0 = *(const float4*)&vl[0][mb];
      float4 v1 = *(const float4*)&vl[1][mb];
      float4 v2 = *(const float4*)&vl[2][mb];
      float4 v3 = *(const float4*)&vl[3][mb];
      a0 = fmaf(w4.x, v0.x, a0); a0 = fmaf(w4.y, v0.y, a0);
      a0 = fmaf(w4.z, v0.z, a0); a0 = fmaf(w4.w, v0.w, a0);
      a1 = fmaf(w4.x, v1.x, a1); a1 = fmaf(w4.y, v1.y, a1);
      a1 = fmaf(w4.z, v1.z, a1); a1 = fmaf(w4.w, v1.w, a1);
      a2 = fmaf(w4.x, v2.x, a2); a2 = fmaf(w4.y, v2.y, a2);
      a2 = fmaf(w4.z, v2.z, a2); a2 = fmaf(w4.w, v2.w, a2);
      a3 = fmaf(w4.x, v3.x, a3); a3 = fmaf(w4.y, v3.y, a3);
      a3 = fmaf(w4.z, v3.z, a3); a3 = fmaf(w4.w, v3.w, a3);
    }
    pacc[grp][0][k] = a0; pacc[grp][1][k] = a1;
    pacc[grp][2][k] = a2; pacc[grp][3][k] = a3;
  }
  __syncthreads();
  float mx = (pacc[0][grp][k] + pacc[1][grp][k]) + (pacc[2][grp][k] + pacc[3][grp][k]);
  float mxn2 = group_sum(mx * mx, red);

  float xn  = fmaxf(sqrtf(xn2), 1e-15f);
  float mxn = fmaxf(sqrtf(mxn2), 1e-15f);
  float r = ftanh(mxn * frcp(xn) * fartanh(xn));
  float res = r * mx * frcp(mxn);

  // proj + (res . hyp_bias) fused
  float2 rp = group_sum2(res * res, res * hbk, red);
  float rn2 = rp.x, xy = rp.y;
  float rn = fmaxf(sqrtf(rn2), 1e-15f);
  float x2 = rn2;
  if (rn > PROJ_R) { float sc = PROJ_R * frcp(rn); res *= sc; xy *= sc; x2 = PROJ_R * PROJ_R; }

  // mobius_add(res, hyp_bias), then proj
  float num = (1.f + 2.f * xy + hb2) * res + (1.f - x2) * hbk;
  float den = fmaxf(1.f + 2.f * xy + x2 * hb2, 1e-15f);
  float hv = num * frcp(den);
  float hn2 = group_sum(hv * hv, red);
  float hn = fmaxf(sqrtf(hn2), 1e-15f);
  float h2 = hn2;
  if (hn > PROJ_R) { hv = hv * frcp(hn) * PROJ_R; h2 = PROJ_R * PROJ_R; }

  h[node * D + k] = hv;
  if (k == 0) nh2[node] = h2;

  // ---- u = att_w1[:, D:2D] @ h, chunk-split ----
  vl[grp][k] = hv;          // prior vl reads are behind >=1 barrier
  __syncthreads();
  {
    const float4* Ar = (const float4*)(aw1 + k * (2 * D) + D + grp * 32);
    float a0 = 0.f, a1 = 0.f, a2 = 0.f, a3 = 0.f;
    #pragma unroll
    for (int m4 = 0; m4 < 8; ++m4) {
      float4 w4 = Ar[m4];
      const int mb = grp * 32 + m4 * 4;
      float4 v0 = *(const float4*)&vl[0][mb];
      float4 v1 = *(const float4*)&vl[1][mb];
      float4 v2 = *(const float4*)&vl[2][mb];
      float4 v3 = *(const float4*)&vl[3][mb];
      a0 = fmaf(w4.x, v0.x, a0); a0 = fmaf(w4.y, v0.y, a0);
      a0 = fmaf(w4.z, v0.z, a0); a0 = fmaf(w4.w, v0.w, a0);
      a1 = fmaf(w4.x, v1.x, a1); a1 = fmaf(w4.y, v1.y, a1);
      a1 = fmaf(w4.z, v1.z, a1); a1 = fmaf(w4.w, v1.w, a1);
      a2 = fmaf(w4.x, v2.x, a2); a2 = fmaf(w4.y, v2.y, a2);
      a2 = fmaf(w4.z, v2.z, a2); a2 = fmaf(w4.w, v2.w, a2);
      a3 = fmaf(w4.x, v3.x, a3); a3 = fmaf(w4.y, v3.y, a3);
      a3 = fmaf(w4.z, v3.z, a3); a3 = fmaf(w4.w, v3.w, a3);
    }
    pacc[grp][0][k] = a0; pacc[grp][1][k] = a1;
    pacc[grp][2][k] = a2; pacc[grp][3][k] = a3;
  }
  __syncthreads();
  u[node * D + k] = (pacc[0][grp][k] + pacc[1][grp][k]) + (pacc[2][grp][k] + pacc[3][grp][k]);
}

// ---------- kernel 2: fused attention (active pairs, 16-lane clusters) ----------
__global__ __launch_bounds__(512) void k_fused(
    const float* __restrict__ h, const float* __restrict__ u,
    const float* __restrict__ nh2, const float* __restrict__ mask,
    const float* __restrict__ ab1, const float* __restrict__ aw2,
    const float* __restrict__ ab2,
    const float* __restrict__ mw1, const float* __restrict__ mb1,
    const float* __restrict__ mw2, const float* __restrict__ mb2,
    float* __restrict__ out) {
  const int t = threadIdx.x;
  const int grp = t >> 7;
  const int k = t & 127;
  const int node = blockIdx.x * 4 + grp;
  const int bb = node >> 8;
  __shared__ __align__(16) float hi[4][D], ui[4][D], b1l[D], w2l[D];
  __shared__ __align__(16) float sl[4][D], gl[4][D];
  __shared__ float wBs[4][N];
  __shared__ int actJ[4][N];
  __shared__ int wcnt[4][4];
  __shared__ int nacts[4];
  __shared__ float red[16];

  // ---- stage per-node vectors ----
  hi[grp][k] = h[node * D + k];
  ui[grp][k] = u[node * D + k];
  if (t < D) { b1l[t] = ab1[t]; w2l[t] = aw2[t]; }

  // ---- deterministic mask compaction ----
  const int lane = t & 63;
  const int wrow = (t >> 6) & 3;
  bool actv[2]; int prev[2];
  #pragma unroll
  for (int r = 0; r < 2; ++r) {
    const int ii = r * 2 + (t >> 8);
    const int j = t & 255;
    float mk = mask[(blockIdx.x * 4 + ii) * N + j];
    bool a = (mk != 0.f);
    unsigned long long bal = __ballot(a);
    actv[r] = a;
    prev[r] = __popcll(bal & ((1ull << lane) - 1ull));
    if (lane == 0) wcnt[ii][wrow] = __popcll(bal);
  }
  __syncthreads();
  #pragma unroll
  for (int r = 0; r < 2; ++r) {
    const int ii = r * 2 + (t >> 8);
    int base = 0;
    for (int w = 0; w < wrow; ++w) base += wcnt[ii][w];
    if (actv[r]) actJ[ii][base + prev[r]] = t & 255;
  }
  if (t < 4) nacts[t] = wcnt[t][0] + wcnt[t][1] + wcnt[t][2] + wcnt[t][3];
  __syncthreads();

  // ---- phase B: 16-lane clusters, 8 pairs in flight per group ----
  const float bias2 = ab2[0];
  const int cla = lane & 15;                      // lane in cluster
  const int cid = ((t >> 6) & 1) * 4 + (lane >> 4); // cluster id in group: 0..7
  const int nact = nacts[grp];
  const float n2i = nh2[node];
  const float beta = 1.f - n2i;
  const float coefb = fmaxf(beta, 1e-15f);

  const float4* hi4 = (const float4*)hi[grp];
  const float4* ui4 = (const float4*)ui[grp];
  const float4 y0 = hi4[cla * 2],               y1 = hi4[cla * 2 + 1];
  const float4 vv0 = ui4[cla * 2],              vv1 = ui4[cla * 2 + 1];
  const float4 bb0 = ((const float4*)b1l)[cla * 2], bb1 = ((const float4*)b1l)[cla * 2 + 1];
  const float4 ww0 = ((const float4*)w2l)[cla * 2], ww1 = ((const float4*)w2l)[cla * 2 + 1];

  float wA_v = 0.f;
  for (int p0 = cid; p0 < nact; p0 += 8) {
    const int j = actJ[grp][p0];
    const int jrow = bb * N + j;
    const float n2j = nh2[jrow];
    const float4* hj = (const float4*)(h + jrow * D);
    const float4* uj = (const float4*)(u + jrow * D);
    float4 x0 = hj[cla * 2], x1 = hj[cla * 2 + 1];
    float4 u0 = uj[cla * 2], u1 = uj[cla * 2 + 1];

    // G partial: 8 elements per lane, cluster-reduce
    float g =          x0.x * y0.x;
    g = fmaf(x0.y, y0.y, g); g = fmaf(x0.z, y0.z, g); g = fmaf(x0.w, y0.w, g);
    g = fmaf(x1.x, y1.x, g); g = fmaf(x1.y, y1.y, g);
    g = fmaf(x1.z, y1.z, g); g = fmaf(x1.w, y1.w, g);
    g += __shfl_xor(g, 1, 64); g += __shfl_xor(g, 2, 64);
    g += __shfl_xor(g, 4, 64); g += __shfl_xor(g, 8, 64);

    // logmap scalars (redundant per lane, cheap)
    float alpha = 1.f - 2.f * g + n2j;
    float den = fmaxf(1.f - 2.f * g + n2i * n2j, 1e-15f);
    float rden = frcp(den);
    float A0 = -alpha * rden, B0 = beta * rden;
    float sn2 = fmaxf(A0 * A0 * n2i + 2.f * A0 * B0 * g + B0 * B0 * n2j, 0.f);
    float sn = fmaxf(sqrtf(sn2), 1e-15f);
    float coef = coefb * fartanh(sn) * frcp(sn);
    float A = coef * A0, Bc = coef * B0;

    // MLP partial: 8 silu terms per lane, cluster-reduce
    float acc =            fsilu(fmaf(A, vv0.x, fmaf(Bc, u0.x, bb0.x))) * ww0.x;
    acc = fmaf(fsilu(fmaf(A, vv0.y, fmaf(Bc, u0.y, bb0.y))), ww0.y, acc);
    acc = fmaf(fsilu(fmaf(A, vv0.z, fmaf(Bc, u0.z, bb0.z))), ww0.z, acc);
    acc = fmaf(fsilu(fmaf(A, vv0.w, fmaf(Bc, u0.w, bb0.w))), ww0.w, acc);
    acc = fmaf(fsilu(fmaf(A, vv1.x, fmaf(Bc, u1.x, bb1.x))), ww1.x, acc);
    acc = fmaf(fsilu(fmaf(A, vv1.y, fmaf(Bc, u1.y, bb1.y))), ww1.y, acc);
    acc = fmaf(fsilu(fmaf(A, vv1.z, fmaf(Bc, u1.z, bb1.z))), ww1.z, acc);
    acc = fmaf(fsilu(fmaf(A, vv1.w, fmaf(Bc, u1.w, bb1.w))), ww1.w, acc);
    acc += __shfl_xor(acc, 1, 64); acc += __shfl_xor(acc, 2, 64);
    acc += __shfl_xor(acc, 4, 64); acc += __shfl_xor(acc, 8, 64);

    if (cla == 0) {
      float w = fsigm(acc + bias2);     // mask == 1 for active pairs
      wBs[grp][p0] = w * Bc;
      wA_v = fmaf(w, A, wA_v);
    }
  }
  float accA = group_sum(wA_v, red);    // syncs also publish wBs

  // ---- phase C: support_t[k] = accA*h_i[k] + sum_p wB[p]*h_j[p][k] ----
  float s0 = accA * hi[grp][k], s1 = 0.f;
  int p = 0;
  for (; p + 2 <= nact; p += 2) {
    s0 = fmaf(wBs[grp][p],     h[(bb * N + actJ[grp][p]) * D + k],     s0);
    s1 = fmaf(wBs[grp][p + 1], h[(bb * N + actJ[grp][p + 1]) * D + k], s1);
  }
  if (p < nact) s0 = fmaf(wBs[grp][p], h[(bb * N + actJ[grp][p]) * D + k], s0);
  sl[grp][k] = s0 + s1;
  __syncthreads();

  // ---- phase D: node MLP (x_self half ~ 0) ----
  const float4* w1r = (const float4*)(mw1 + k * (2 * D) + D);
  float a0 = mb1[k], a1 = 0.f;
  #pragma unroll 8
  for (int m4 = 0; m4 < D / 4; ++m4) {
    float4 w4 = w1r[m4];
    const float4 sv = *(const float4*)&sl[grp][m4 * 4];
    a0 = fmaf(w4.x, sv.x, a0); a1 = fmaf(w4.y, sv.y, a1);
    a0 = fmaf(w4.z, sv.z, a0); a1 = fmaf(w4.w, sv.w, a1);
  }
  gl[grp][k] = fsilu(a0 + a1);
  __syncthreads();
  const float4* w2r = (const float4*)(mw2 + k * D);
  float c0 = mb2[k], c1 = 0.f;
  #pragma unroll 8
  for (int m4 = 0; m4 < D / 4; ++m4) {
    float4 w4 = w2r[m4];
    const float4 gv = *(const float4*)&gl[grp][m4 * 4];
    c0 = fmaf(w4.x, gv.x, c0); c1 = fmaf(w4.y, gv.y, c1);
    c0 = fmaf(w4.z, gv.z, c0); c1 = fmaf(w4.w, gv.w, c1);
  }
  float s2 = c0 + c1;

  // ---- phase E: expmap(s2, h) -> proj -> HypAct (analytic norms) ----
  const float hk = hi[grp][k];
  const float n2p = nh2[node];
  float2 us = group_sum2(s2 * s2, hk * s2, red);
  float un = fmaxf(sqrtf(us.x), 1e-15f);
  float lam = 2.f * frcp(fmaxf(1.f - n2p, 1e-15f));
  float th = ftanh(0.5f * lam * un);
  float ssc = th * frcp(un);
  float second = ssc * s2;
  float y2 = th * th;
  float xy = ssc * us.y;

  float num = (1.f + 2.f * xy + y2) * hk + (1.f - n2p) * second;
  float den = fmaxf(1.f + 2.f * xy + n2p * y2, 1e-15f);
  float o = num * frcp(den);

  float on2 = group_sum(o * o, red);
  float on = fmaxf(sqrtf(on2), 1e-15f);
  float pn = on;
  if (on > PROJ_R) { o *= PROJ_R * frcp(on); pn = PROJ_R; }

  float xt = fartanh(pn) * frcp(pn) * o;
  xt = fsilu(xt);
  float xn2 = group_sum(xt * xt, red);
  float xn = fmaxf(sqrtf(xn2), 1e-15f);
  float tx = ftanh(xn);
  float o2 = tx * frcp(xn) * xt;
  if (tx > PROJ_R) o2 *= PROJ_R * frcp(tx);

  out[node * D + k] = o2;
}

// ---------- launch ----------
extern "C" void kernel_launch(void* const* d_in, const int* in_sizes, int n_in,
                              void* d_out, int out_size, void* d_ws, size_t ws_size,
                              hipStream_t stream) {
  const float* x     = (const float*)d_in[0];
  const float* mask  = (const float*)d_in[1];
  const float* W     = (const float*)d_in[2];
  const float* b_lin = (const float*)d_in[3];
  const float* aw1   = (const float*)d_in[4];
  const float* ab1   = (const float*)d_in[5];
  const float* aw2   = (const float*)d_in[6];
  const float* ab2   = (const float*)d_in[7];
  const float* mw1   = (const float*)d_in[8];
  const float* mb1   = (const float*)d_in[9];
  const float* mw2   = (const float*)d_in[10];
  const float* mb2   = (const float*)d_in[11];
  float* out = (float*)d_out;

  float* ws  = (float*)d_ws;
  float* h   = ws;               // B*N*D = 131072
  float* u   = h + B * N * D;    // B*N*D = 131072
  float* nh2 = u + B * N * D;    // B*N   = 1024

  hipLaunchKernelGGL(k_node, dim3(B * N / 4), dim3(512), 0, stream,
                     x, W, aw1, b_lin, h, u, nh2);
  hipLaunchKernelGGL(k_fused, dim3(B * N / 4), dim3(512), 0, stream,
                     h, u, nh2, mask, ab1, aw2, ab2, mw1, mb1, mw2, mb2, out);
}